// Round 1
// 458.626 us; speedup vs baseline: 1.0500x; 1.0500x over previous
//
#include <hip/hip_runtime.h>

#define NNODES 1700
#define CDIM   256

typedef __attribute__((ext_vector_type(8))) short bf16x8;
typedef __attribute__((ext_vector_type(4))) float f32x4;

__device__ inline float bf2f(unsigned h) { return __uint_as_float(h << 16); }
__device__ inline unsigned short f2bf(float f) {
  unsigned u = __float_as_uint(f);
  u = (u + 0x7FFFu + ((u >> 16) & 1u)) >> 16;  // RNE
  return (unsigned short)u;
}

__device__ inline void async_copy16(const void* gsrc, void* ldst) {
  __builtin_amdgcn_global_load_lds(
      (const __attribute__((address_space(1))) unsigned int*)gsrc,
      (__attribute__((address_space(3))) unsigned int*)ldst,
      16, 0, 0);
}

// ---------------- graph preprocessing ----------------

__global__ void zero_kernel(int* p, int n) {
  int i = blockIdx.x * blockDim.x + threadIdx.x;
  if (i < n) p[i] = 0;
}

// edge_index layout [2, E] row-major: sources [0..E), destinations [E..2E)
__global__ void count_kernel(const int* __restrict__ ei, int E, int* __restrict__ cnt) {
  int i = blockIdx.x * blockDim.x + threadIdx.x;
  if (i < E) atomicAdd(&cnt[ei[E + i]], 1);
}

__global__ void dinv_kernel(const int* __restrict__ cnt, float* __restrict__ dinv, int n) {
  int i = blockIdx.x * blockDim.x + threadIdx.x;
  if (i < n) dinv[i] = rsqrtf((float)(cnt[i] + 1));  // +1 self-loop; deg >= 1
}

// exclusive scan of (cnt[i]+1) over N=1700 -> off[0..N]; single block, 1024 thr, 2048 slots
__global__ __launch_bounds__(1024) void scan_kernel(const int* __restrict__ cnt, int n,
                                                    int* __restrict__ off) {
  __shared__ int s[2048];
  int t = threadIdx.x;
  for (int i = t; i < 2048; i += 1024) s[i] = (i < n) ? (cnt[i] + 1) : 0;
  for (int d = 1; d < 2048; d <<= 1) {
    __syncthreads();
    int idx = (t + 1) * (d << 1) - 1;
    if (idx < 2048) s[idx] += s[idx - d];
  }
  __syncthreads();
  if (t == 0) s[2047] = 0;
  for (int d = 1024; d >= 1; d >>= 1) {
    __syncthreads();
    int idx = (t + 1) * (d << 1) - 1;
    if (idx < 2048) { int tmp = s[idx - d]; s[idx - d] = s[idx]; s[idx] += tmp; }
  }
  __syncthreads();
  for (int i = t; i <= n; i += 1024) off[i] = s[i];
}

__global__ void fill_kernel(const int* __restrict__ ei, int E, int n,
                            const float* __restrict__ dinv, const int* __restrict__ off,
                            int* __restrict__ cursor, int* __restrict__ srcv,
                            float* __restrict__ wv) {
  int i = blockIdx.x * blockDim.x + threadIdx.x;
  if (i >= E + n) return;
  int s, d;
  if (i < E) { s = ei[i]; d = ei[E + i]; } else { s = d = i - E; }
  float w = dinv[s] * dinv[d];
  int p = atomicAdd(&cursor[d], 1);
  int idx = off[d] + p;
  srcv[idx] = s;
  wv[idx] = w;
}

// W f32 [k][n] row-major -> Wt bf16 [n][k]
__global__ void transpose_kernel(const float* __restrict__ W,
                                 unsigned short* __restrict__ Wt) {
  int i = blockIdx.x * 256 + threadIdx.x;  // 65536 elems
  int k = i >> 8, n = i & 255;
  Wt[n * 256 + k] = f2bf(W[i]);
}

// f32 -> bf16 streaming convert (8 elems/thread, exact coverage)
__global__ __launch_bounds__(256) void cvt_kernel(const float* __restrict__ x,
                                                  unsigned short* __restrict__ o) {
  size_t i = ((size_t)blockIdx.x * 256 + threadIdx.x) * 8;
  float4 f0 = *(const float4*)(x + i);
  float4 f1 = *(const float4*)(x + i + 4);
  bf16x8 p;
  p[0] = (short)f2bf(f0.x); p[1] = (short)f2bf(f0.y);
  p[2] = (short)f2bf(f0.z); p[3] = (short)f2bf(f0.w);
  p[4] = (short)f2bf(f1.x); p[5] = (short)f2bf(f1.y);
  p[6] = (short)f2bf(f1.z); p[7] = (short)f2bf(f1.w);
  *(bf16x8*)(o + i) = p;
}

// ---------------- GEMM: H[M][256] = A[M][256] @ W ; A bf16, Wt bf16 W^T [n][k] --------------
// 128x256 tile (full N), 8 waves (2x4, 64x64 each), BK=32, 8 K-steps.
// Counted-vmcnt pipeline: 3 LDS buffers, depth-2 prefetch, 1 barrier/step, vmcnt never 0
// in steady state (T3+T4). All loop VMEM = global_load_lds (3/thread/step, exact count).

template <int K>
__device__ __forceinline__ void kstep(const unsigned short* __restrict__ asrc,
                                      const unsigned short* __restrict__ bsrc,
                                      unsigned short (&As)[3][128 * 32],
                                      unsigned short (&Bs)[3][256 * 32],
                                      int t, int wm, int wn, int lr, int lk,
                                      f32x4 (&acc)[4][4]) {
  // stage K issued 2 steps ago; leave {K+1, K+2} (3 loads each) in flight
  if constexpr (K < 7) {
    asm volatile("s_waitcnt vmcnt(3)" ::: "memory");
  } else {
    asm volatile("s_waitcnt vmcnt(0)" ::: "memory");
  }
  __builtin_amdgcn_s_barrier();  // raw barrier: no auto vmcnt(0) drain
  if constexpr (K + 2 < 8) {
    constexpr int S = K + 2;
    async_copy16(asrc + S * 32, &As[S % 3][t * 8]);
    async_copy16(bsrc + S * 32, &Bs[S % 3][t * 8]);
    async_copy16(bsrc + 128 * CDIM + S * 32, &Bs[S % 3][4096 + t * 8]);
  }
  bf16x8 a[4], b[4];
#pragma unroll
  for (int i = 0; i < 4; i++)
    a[i] = *(const bf16x8*)&As[K % 3][(wm + i * 16 + lr) * 32 + lk];
#pragma unroll
  for (int i = 0; i < 4; i++)
    b[i] = *(const bf16x8*)&Bs[K % 3][(wn + i * 16 + lr) * 32 + lk];
#pragma unroll
  for (int mi = 0; mi < 4; mi++)
#pragma unroll
    for (int ni = 0; ni < 4; ni++)
      acc[mi][ni] = __builtin_amdgcn_mfma_f32_16x16x32_bf16(a[mi], b[ni], acc[mi][ni], 0, 0, 0);
}

__global__ __launch_bounds__(512, 4) void gemm_n256(const unsigned short* __restrict__ A,
                                                    const unsigned short* __restrict__ Wt,
                                                    unsigned short* __restrict__ H) {
  __shared__ __align__(16) unsigned short As[3][128 * 32];  // 24 KB
  __shared__ __align__(16) unsigned short Bs[3][256 * 32];  // 48 KB
  const int m0 = blockIdx.x * 128;
  const int t = threadIdx.x;
  const int lane = t & 63;
  const int w = t >> 6;
  const int wm = (w & 1) * 64;
  const int wn = (w >> 1) * 64;
  const int lr = lane & 15;
  const int lk = (lane >> 4) * 8;

  // staging: 16B chunk c covers row c>>2, k-off (c&3)*8. A: chunks 0..511 (t).
  // B: chunks t (rows 0..127) and t+512 (rows 128..255).
  const unsigned short* asrc = A + (size_t)(m0 + (t >> 2)) * CDIM + (t & 3) * 8;
  const unsigned short* bsrc = Wt + (size_t)(t >> 2) * CDIM + (t & 3) * 8;

  f32x4 acc[4][4] = {};

#pragma unroll
  for (int s = 0; s < 2; s++) {  // prologue: stages 0,1 in flight
    async_copy16(asrc + s * 32, &As[s][t * 8]);
    async_copy16(bsrc + s * 32, &Bs[s][t * 8]);
    async_copy16(bsrc + 128 * CDIM + s * 32, &Bs[s][4096 + t * 8]);
  }

  kstep<0>(asrc, bsrc, As, Bs, t, wm, wn, lr, lk, acc);
  kstep<1>(asrc, bsrc, As, Bs, t, wm, wn, lr, lk, acc);
  kstep<2>(asrc, bsrc, As, Bs, t, wm, wn, lr, lk, acc);
  kstep<3>(asrc, bsrc, As, Bs, t, wm, wn, lr, lk, acc);
  kstep<4>(asrc, bsrc, As, Bs, t, wm, wn, lr, lk, acc);
  kstep<5>(asrc, bsrc, As, Bs, t, wm, wn, lr, lk, acc);
  kstep<6>(asrc, bsrc, As, Bs, t, wm, wn, lr, lk, acc);
  kstep<7>(asrc, bsrc, As, Bs, t, wm, wn, lr, lk, acc);

  const int orow = (lane >> 4) * 4;  // C/D: col=lane&15, row=(lane>>4)*4+r  [m89/m91]
#pragma unroll
  for (int mi = 0; mi < 4; mi++) {
#pragma unroll
    for (int ni = 0; ni < 4; ni++) {
#pragma unroll
      for (int r = 0; r < 4; r++) {
        int gr = m0 + wm + mi * 16 + orow + r;
        int gc = wn + ni * 16 + lr;
        H[(size_t)gr * CDIM + gc] = f2bf(acc[mi][ni][r]);
      }
    }
  }
}

// ---------------- aggregation: out[b,n,:] = relu(sum_e w_e * H[b,src_e,:] + bias (+resid)) ----
// grid (NNODES, B/8), block 256: 8 batches x 32 lanes x 8 channels (16B gathers).
// FINAL: add f32 residual, write f32 out. else: write bf16 out.

template <bool FINAL>
__global__ __launch_bounds__(256) void agg_kernel(const unsigned short* __restrict__ H,
                                                  const int* __restrict__ off,
                                                  const int* __restrict__ srcv,
                                                  const float* __restrict__ wv,
                                                  const float* __restrict__ bias,
                                                  const float* __restrict__ resid,
                                                  void* __restrict__ outp) {
  const int n = blockIdx.x;
  const int b = blockIdx.y * 8 + (threadIdx.x >> 5);
  const int c = (threadIdx.x & 31) * 8;
  const int beg = off[n], end = off[n + 1];

  float a0 = 0.f, a1 = 0.f, a2 = 0.f, a3 = 0.f;
  float a4 = 0.f, a5 = 0.f, a6 = 0.f, a7 = 0.f;
  for (int i = beg; i < end; i++) {
    int s = srcv[i];
    float w = wv[i];
    uint4 v = *(const uint4*)(H + ((size_t)b * NNODES + s) * CDIM + c);
    a0 += w * bf2f(v.x & 0xffffu); a1 += w * bf2f(v.x >> 16);
    a2 += w * bf2f(v.y & 0xffffu); a3 += w * bf2f(v.y >> 16);
    a4 += w * bf2f(v.z & 0xffffu); a5 += w * bf2f(v.z >> 16);
    a6 += w * bf2f(v.w & 0xffffu); a7 += w * bf2f(v.w >> 16);
  }
  float4 bv0 = *(const float4*)(bias + c);
  float4 bv1 = *(const float4*)(bias + c + 4);
  a0 += bv0.x; a1 += bv0.y; a2 += bv0.z; a3 += bv0.w;
  a4 += bv1.x; a5 += bv1.y; a6 += bv1.z; a7 += bv1.w;

  const size_t o = ((size_t)b * NNODES + n) * CDIM + c;
  if (FINAL) {
    float4 r0 = *(const float4*)(resid + o);
    float4 r1 = *(const float4*)(resid + o + 4);
    a0 += r0.x; a1 += r0.y; a2 += r0.z; a3 += r0.w;
    a4 += r1.x; a5 += r1.y; a6 += r1.z; a7 += r1.w;
  }
  a0 = fmaxf(a0, 0.f); a1 = fmaxf(a1, 0.f); a2 = fmaxf(a2, 0.f); a3 = fmaxf(a3, 0.f);
  a4 = fmaxf(a4, 0.f); a5 = fmaxf(a5, 0.f); a6 = fmaxf(a6, 0.f); a7 = fmaxf(a7, 0.f);

  if (FINAL) {
    float4 o0, o1;
    o0.x = a0; o0.y = a1; o0.z = a2; o0.w = a3;
    o1.x = a4; o1.y = a5; o1.z = a6; o1.w = a7;
    *(float4*)((float*)outp + o) = o0;
    *(float4*)((float*)outp + o + 4) = o1;
  } else {
    bf16x8 ov;
    ov[0] = (short)f2bf(a0); ov[1] = (short)f2bf(a1);
    ov[2] = (short)f2bf(a2); ov[3] = (short)f2bf(a3);
    ov[4] = (short)f2bf(a4); ov[5] = (short)f2bf(a5);
    ov[6] = (short)f2bf(a6); ov[7] = (short)f2bf(a7);
    *(bf16x8*)((unsigned short*)outp + o) = ov;
  }
}

// ---------------- launch ----------------

extern "C" void kernel_launch(void* const* d_in, const int* in_sizes, int n_in,
                              void* d_out, int out_size, void* d_ws, size_t ws_size,
                              hipStream_t stream) {
  const float* x  = (const float*)d_in[0];
  const float* W1 = (const float*)d_in[1];
  const float* b1 = (const float*)d_in[2];
  const float* W2 = (const float*)d_in[3];
  const float* b2 = (const float*)d_in[4];
  const float* W3 = (const float*)d_in[5];
  const float* b3 = (const float*)d_in[6];
  const int* esp = (const int*)d_in[7];
  const int* etm = (const int*)d_in[8];

  const int Esp = in_sizes[7] / 2;
  const int Etm = in_sizes[8] / 2;
  const int B = in_sizes[0] / (NNODES * CDIM);
  const int M = B * NNODES;

  char* ws = (char*)d_ws;
  size_t woff = 0;
  auto alloc = [&](size_t bytes) -> void* {
    void* p = ws + woff;
    woff = (woff + bytes + 255) & ~(size_t)255;
    return p;
  };

  unsigned short* H   = (unsigned short*)alloc((size_t)M * CDIM * 2);  // 55.7 MB bf16
  unsigned short* Act = (unsigned short*)alloc((size_t)M * CDIM * 2);  // 55.7 MB bf16
  unsigned short* Wt  = (unsigned short*)alloc((size_t)3 * CDIM * CDIM * 2);
  int* zero_base = (int*)alloc((size_t)4 * NNODES * sizeof(int));
  int* cnt_sp = zero_base;
  int* cur_sp = zero_base + NNODES;
  int* cnt_tm = zero_base + 2 * NNODES;
  int* cur_tm = zero_base + 3 * NNODES;
  int* off_sp = (int*)alloc((NNODES + 1) * sizeof(int));
  int* off_tm = (int*)alloc((NNODES + 1) * sizeof(int));
  float* dinv_sp = (float*)alloc(NNODES * sizeof(float));
  float* dinv_tm = (float*)alloc(NNODES * sizeof(float));
  int*   src_sp = (int*)alloc((size_t)(Esp + NNODES) * sizeof(int));
  float* wgt_sp = (float*)alloc((size_t)(Esp + NNODES) * sizeof(float));
  int*   src_tm = (int*)alloc((size_t)(Etm + NNODES) * sizeof(int));
  float* wgt_tm = (float*)alloc((size_t)(Etm + NNODES) * sizeof(float));

  // graph preprocessing
  zero_kernel<<<(4 * NNODES + 255) / 256, 256, 0, stream>>>(zero_base, 4 * NNODES);
  transpose_kernel<<<256, 256, 0, stream>>>(W1, Wt);
  transpose_kernel<<<256, 256, 0, stream>>>(W2, Wt + CDIM * CDIM);
  transpose_kernel<<<256, 256, 0, stream>>>(W3, Wt + 2 * CDIM * CDIM);
  count_kernel<<<(Esp + 255) / 256, 256, 0, stream>>>(esp, Esp, cnt_sp);
  count_kernel<<<(Etm + 255) / 256, 256, 0, stream>>>(etm, Etm, cnt_tm);
  dinv_kernel<<<(NNODES + 255) / 256, 256, 0, stream>>>(cnt_sp, dinv_sp, NNODES);
  dinv_kernel<<<(NNODES + 255) / 256, 256, 0, stream>>>(cnt_tm, dinv_tm, NNODES);
  scan_kernel<<<1, 1024, 0, stream>>>(cnt_sp, NNODES, off_sp);
  scan_kernel<<<1, 1024, 0, stream>>>(cnt_tm, NNODES, off_tm);
  fill_kernel<<<(Esp + NNODES + 255) / 256, 256, 0, stream>>>(esp, Esp, NNODES, dinv_sp,
                                                              off_sp, cur_sp, src_sp, wgt_sp);
  fill_kernel<<<(Etm + NNODES + 255) / 256, 256, 0, stream>>>(etm, Etm, NNODES, dinv_tm,
                                                              off_tm, cur_tm, src_tm, wgt_tm);

  dim3 ggrid(M / 128);
  dim3 agrid(NNODES, B / 8);

  // x f32 -> bf16 into Act (Act is dead until agg1 writes it; GEMM1 consumes it first)
  cvt_kernel<<<(M * CDIM / 8 + 255) / 256, 256, 0, stream>>>(x, Act);

  // layer 1 (spatial edges)
  gemm_n256<<<ggrid, 512, 0, stream>>>(Act, Wt, H);
  agg_kernel<false><<<agrid, 256, 0, stream>>>(H, off_sp, src_sp, wgt_sp, b1, nullptr, Act);
  // layer 2 (temporal edges)
  gemm_n256<<<ggrid, 512, 0, stream>>>(Act, Wt + CDIM * CDIM, H);
  agg_kernel<false><<<agrid, 256, 0, stream>>>(H, off_tm, src_tm, wgt_tm, b2, nullptr, Act);
  // layer 3 (spatial edges) + residual + relu -> f32 d_out
  gemm_n256<<<ggrid, 512, 0, stream>>>(Act, Wt + 2 * CDIM * CDIM, H);
  agg_kernel<true><<<agrid, 256, 0, stream>>>(H, off_sp, src_sp, wgt_sp, b3, x, d_out);
}